// Round 5
// baseline (1653.801 us; speedup 1.0000x reference)
//
#include <hip/hip_runtime.h>
#include <hip/hip_bf16.h>

typedef __hip_bfloat16 bf16;
typedef __attribute__((ext_vector_type(8))) __bf16 bf16x8;
typedef __attribute__((ext_vector_type(4))) float floatx4;

#define BUCKET_SHIFT 7
#define BUCKET_NODES 128
#define MAX_NB 1024

__device__ __forceinline__ unsigned short f2b(float f) {
    bf16 h = __float2bfloat16(f);
    unsigned short s;
    __builtin_memcpy(&s, &h, 2);
    return s;
}
__device__ __forceinline__ float b2f(unsigned short u) {
    unsigned int x = ((unsigned int)u) << 16;
    float f;
    __builtin_memcpy(&f, &x, 4);
    return f;
}
__device__ __forceinline__ float load_dual(const void* p, long long i, bool isbf) {
    return isbf ? b2f(((const unsigned short*)p)[i]) : ((const float*)p)[i];
}
__device__ __forceinline__ bf16x8 ldsfrag(const unsigned short* p) {
    union { uint4 u; bf16x8 v; } t;
    t.u = *(const uint4*)p;
    return t.v;
}

// ---------------------------------------------------------------------------
// Dtype detection: flag=1 if float arrays are bf16-packed, 0 if true f32.
// ---------------------------------------------------------------------------
__global__ __launch_bounds__(64) void detect_kernel(const unsigned int* __restrict__ words,
                                                    int* __restrict__ flag) {
    int cnt = 0;
    for (int i = threadIdx.x; i < 4096; i += 64) {
        unsigned int lo = words[i] & 0xFFFFu;
        unsigned int e = (lo >> 7) & 0xFFu;
        if (lo == 0u || (e >= 110u && e <= 135u)) cnt++;
    }
#pragma unroll
    for (int off = 32; off > 0; off >>= 1) cnt += __shfl_down(cnt, off, 64);
    if (threadIdx.x == 0) *flag = (cnt > 2458) ? 1 : 0;
}

// ---------------------------------------------------------------------------
// W[K][128] (dual) -> Wt bf16-bits [128][K]
// ---------------------------------------------------------------------------
__global__ __launch_bounds__(256) void transpose_w_kernel(const void* __restrict__ W,
                                                          unsigned short* __restrict__ Wt,
                                                          const int* __restrict__ flag, int K) {
    bool isbf = (*flag != 0);
    int idx = blockIdx.x * 256 + threadIdx.x;
    if (idx >= 128 * K) return;
    int n = idx / K, k = idx - n * K;
    Wt[idx] = f2b(load_dual(W, (long long)k * 128 + n, isbf));
}

// ---------------------------------------------------------------------------
// Bucket histogram (LDS-aggregated): bcount[dst>>7]++
// Block = 8192 edges, 256 threads x 32.
// ---------------------------------------------------------------------------
__global__ __launch_bounds__(256) void bhist_kernel(const int* __restrict__ dst,
                                                    int* __restrict__ bcount, int E) {
    __shared__ int lcnt[MAX_NB];
    for (int i = threadIdx.x; i < MAX_NB; i += 256) lcnt[i] = 0;
    __syncthreads();
    int base = blockIdx.x * 8192;
#pragma unroll
    for (int j = 0; j < 32; ++j) {
        int e = base + j * 256 + threadIdx.x;
        if (e < E) atomicAdd(&lcnt[dst[e] >> BUCKET_SHIFT], 1);
    }
    __syncthreads();
    for (int i = threadIdx.x; i < MAX_NB; i += 256)
        if (lcnt[i]) atomicAdd(&bcount[i], lcnt[i]);
}

// ---------------------------------------------------------------------------
// Single-block exclusive scan of bucket counts (NB <= 1024) -> bstart, bcursor
// ---------------------------------------------------------------------------
__global__ __launch_bounds__(256) void bscan_kernel(const int* __restrict__ bcount,
                                                    int* __restrict__ bstart,
                                                    int* __restrict__ bcursor, int NB) {
    int t = threadIdx.x;
    int v[4];
    int sum = 0;
#pragma unroll
    for (int j = 0; j < 4; ++j) {
        int i = t * 4 + j;
        v[j] = (i < NB) ? bcount[i] : 0;
        sum += v[j];
    }
    int lane = t & 63, wave = t >> 6;
    int inc = sum;
#pragma unroll
    for (int off = 1; off < 64; off <<= 1) {
        int x = __shfl_up(inc, off, 64);
        if (lane >= off) inc += x;
    }
    __shared__ int wsum[4];
    if (lane == 63) wsum[wave] = inc;
    __syncthreads();
    int woff = 0;
    for (int w = 0; w < wave; ++w) woff += wsum[w];
    int run = inc - sum + woff;
#pragma unroll
    for (int j = 0; j < 4; ++j) {
        int i = t * 4 + j;
        if (i < NB) { bstart[i] = run; bcursor[i] = run; }
        run += v[j];
    }
}

// ---------------------------------------------------------------------------
// Bucket append: write uint2 records { src | dstLocal<<24, bits(exp(logit)) }
// into per-bucket regions. Per-block chunk reservation via LDS counters keeps
// writes dense (~10 records/bucket/block) -> low write amplification.
// ---------------------------------------------------------------------------
__global__ __launch_bounds__(256) void bappend_kernel(const int* __restrict__ dst,
                                                      const int* __restrict__ src,
                                                      const void* __restrict__ logits,
                                                      int* __restrict__ bcursor,
                                                      uint2* __restrict__ ebuf,
                                                      const int* __restrict__ flag, int E) {
    __shared__ int lcnt[MAX_NB];
    __shared__ int lbase[MAX_NB];
    for (int i = threadIdx.x; i < MAX_NB; i += 256) lcnt[i] = 0;
    __syncthreads();
    const bool isbf = (*flag != 0);
    int base = blockIdx.x * 8192;
#pragma unroll
    for (int j = 0; j < 32; ++j) {
        int e = base + j * 256 + threadIdx.x;
        if (e < E) atomicAdd(&lcnt[dst[e] >> BUCKET_SHIFT], 1);
    }
    __syncthreads();
    for (int i = threadIdx.x; i < MAX_NB; i += 256) {
        int c = lcnt[i];
        if (c) { lbase[i] = atomicAdd(&bcursor[i], c); lcnt[i] = 0; }
    }
    __syncthreads();
#pragma unroll
    for (int j = 0; j < 32; ++j) {
        int e = base + j * 256 + threadIdx.x;
        if (e < E) {
            int d = dst[e];
            int b = d >> BUCKET_SHIFT;
            float w = expf(load_dual(logits, e, isbf));
            int pos = lbase[b] + atomicAdd(&lcnt[b], 1);
            uint2 rec;
            rec.x = (unsigned int)src[e] | ((unsigned int)(d & (BUCKET_NODES - 1)) << 24);
            rec.y = __float_as_uint(w);
            ebuf[pos] = rec;
        }
    }
}

// ---------------------------------------------------------------------------
// Fused aggregation: one block per 128-node bucket. 64 KB LDS f32 accumulator,
// z inline. Wave walks the bucket's records 8-edges-unrolled (8 gathers in
// flight). Writes ctx = elu(acc/z) bf16, coalesced.
// ---------------------------------------------------------------------------
__global__ __launch_bounds__(256) void agg_fused_kernel(const uint2* __restrict__ ebuf,
                                                        const int* __restrict__ bstart,
                                                        const int* __restrict__ bcount,
                                                        const unsigned int* __restrict__ hv32,
                                                        unsigned int* __restrict__ ctx32, int N) {
    __shared__ float acc[BUCKET_NODES * 128];
    __shared__ float zz[BUCKET_NODES];
    for (int i = threadIdx.x; i < BUCKET_NODES * 128; i += 256) acc[i] = 0.f;
    for (int i = threadIdx.x; i < BUCKET_NODES; i += 256) zz[i] = 0.f;
    __syncthreads();

    const int b = blockIdx.x;
    const int s0 = bstart[b];
    const int cnt = bcount[b];
    const int wid = threadIdx.x >> 6;
    const int lane = threadIdx.x & 63;

    for (int i = wid * 8; i < cnt; i += 32) {
        uint2 rec[8];
        unsigned int h[8];
        float w[8];
        int dl[8];
#pragma unroll
        for (int j = 0; j < 8; ++j) {
            int e = i + j;
            int ec = e < cnt ? e : cnt - 1;
            rec[j] = ebuf[s0 + ec];
        }
#pragma unroll
        for (int j = 0; j < 8; ++j) {
            int sv = rec[j].x & 0xFFFFFu;
            dl[j] = rec[j].x >> 24;
            w[j] = (i + j < cnt) ? __uint_as_float(rec[j].y) : 0.f;
            h[j] = hv32[(size_t)sv * 64 + lane];
        }
#pragma unroll
        for (int j = 0; j < 8; ++j) {
            float fx = b2f((unsigned short)h[j]);
            float fy = b2f((unsigned short)(h[j] >> 16));
            atomicAdd(&acc[dl[j] * 128 + 2 * lane], w[j] * fx);
            atomicAdd(&acc[dl[j] * 128 + 2 * lane + 1], w[j] * fy);
            if (lane == 0) atomicAdd(&zz[dl[j]], w[j]);
        }
    }
    __syncthreads();

    // epilogue: 128 nodes x 64 bf162 words, coalesced
    for (int idx = threadIdx.x; idx < BUCKET_NODES * 64; idx += 256) {
        int nl = idx >> 6;
        int l = idx & 63;
        int gn = b * BUCKET_NODES + nl;
        if (gn < N) {
            float z = zz[nl];
            float rz = (z > 0.f) ? 1.f / z : 0.f;
            float x = acc[nl * 128 + 2 * l] * rz;
            float y = acc[nl * 128 + 2 * l + 1] * rz;
            x = x > 0.f ? x : expm1f(x);
            y = y > 0.f ? y : expm1f(y);
            ctx32[(size_t)gn * 64 + l] = ((unsigned int)f2b(y) << 16) | f2b(x);
        }
    }
}

// ---------------------------------------------------------------------------
// MFMA GEMM: out[N,128] = act( A[N,K] @ W[K,128] + b ), W given as Wt[128][K].
// Block: 128 rows x 128 cols, 4 waves; wave = 2x8 tiles of 16x16, K-chunk 64.
// MODE 1: A = concat(ctx bf16 [N,128], A [N,128]), K=256.
// ---------------------------------------------------------------------------
template <int K, int MODE, bool RELU, bool A_DUAL, bool OUT_DUAL>
__global__ __launch_bounds__(256) void gemm_mfma(const void* __restrict__ A,
                                                 const unsigned short* __restrict__ Actx,
                                                 const unsigned short* __restrict__ Wt,
                                                 const void* __restrict__ bias,
                                                 void* __restrict__ outp,
                                                 const int* __restrict__ flag, int N) {
    __shared__ unsigned short Alds[128 * 72];
    __shared__ unsigned short Wlds[128 * 72];
    const bool isbf = (*flag != 0);
    const int t = threadIdx.x;
    const int wid = t >> 6;
    const int lane = t & 63;
    const int m16 = lane & 15;
    const int quad = lane >> 4;
    const int row0 = blockIdx.x * 128;

    floatx4 acc[2][8];
#pragma unroll
    for (int i = 0; i < 2; ++i)
#pragma unroll
        for (int j = 0; j < 8; ++j) acc[i][j] = (floatx4){0.f, 0.f, 0.f, 0.f};

    const int r  = t >> 1;
    const int kh = (t & 1) * 32;

#pragma unroll
    for (int kc = 0; kc < K / 64; ++kc) {
        {
            const unsigned short* wp = Wt + (size_t)r * K + kc * 64 + kh;
            uint4* o = (uint4*)&Wlds[r * 72 + kh];
            o[0] = ((const uint4*)wp)[0];
            o[1] = ((const uint4*)wp)[1];
            o[2] = ((const uint4*)wp)[2];
            o[3] = ((const uint4*)wp)[3];
        }
        {
            int grow = row0 + r;
            if (grow >= N) grow = N - 1;
            uint4* o = (uint4*)&Alds[r * 72 + kh];
            if (MODE == 1 && kc < 2) {
                const unsigned short* ap = Actx + (size_t)grow * 128 + kc * 64 + kh;
                o[0] = ((const uint4*)ap)[0];
                o[1] = ((const uint4*)ap)[1];
                o[2] = ((const uint4*)ap)[2];
                o[3] = ((const uint4*)ap)[3];
            } else {
                const int stride = (MODE == 1) ? 128 : K;
                const int kabs = (MODE == 1) ? (kc * 64 - 128 + kh) : (kc * 64 + kh);
                if (A_DUAL && !isbf) {
                    const float* ap = (const float*)A + (size_t)grow * stride + kabs;
#pragma unroll
                    for (int q = 0; q < 4; ++q) {
                        float4 v0 = ((const float4*)ap)[2 * q];
                        float4 v1 = ((const float4*)ap)[2 * q + 1];
                        union { uint4 u; unsigned short s[8]; } P;
                        P.s[0] = f2b(v0.x); P.s[1] = f2b(v0.y);
                        P.s[2] = f2b(v0.z); P.s[3] = f2b(v0.w);
                        P.s[4] = f2b(v1.x); P.s[5] = f2b(v1.y);
                        P.s[6] = f2b(v1.z); P.s[7] = f2b(v1.w);
                        o[q] = P.u;
                    }
                } else {
                    const unsigned short* ap = (const unsigned short*)A + (size_t)grow * stride + kabs;
                    o[0] = ((const uint4*)ap)[0];
                    o[1] = ((const uint4*)ap)[1];
                    o[2] = ((const uint4*)ap)[2];
                    o[3] = ((const uint4*)ap)[3];
                }
            }
        }
        __syncthreads();

#pragma unroll
        for (int c = 0; c < 2; ++c) {
            const int ko = c * 32 + quad * 8;
            bf16x8 a0 = ldsfrag(&Alds[(wid * 32 + m16) * 72 + ko]);
            bf16x8 a1 = ldsfrag(&Alds[(wid * 32 + 16 + m16) * 72 + ko]);
#pragma unroll
            for (int nt = 0; nt < 8; ++nt) {
                bf16x8 bb = ldsfrag(&Wlds[(nt * 16 + m16) * 72 + ko]);
                acc[0][nt] = __builtin_amdgcn_mfma_f32_16x16x32_bf16(a0, bb, acc[0][nt], 0, 0, 0);
                acc[1][nt] = __builtin_amdgcn_mfma_f32_16x16x32_bf16(a1, bb, acc[1][nt], 0, 0, 0);
            }
        }
        __syncthreads();
    }

#pragma unroll
    for (int mt = 0; mt < 2; ++mt) {
        int gr0 = row0 + wid * 32 + mt * 16 + quad * 4;
#pragma unroll
        for (int nt = 0; nt < 8; ++nt) {
            int col = nt * 16 + m16;
            float bb = load_dual(bias, col, isbf);
#pragma unroll
            for (int rg = 0; rg < 4; ++rg) {
                int gr = gr0 + rg;
                if (gr < N) {
                    float x = acc[mt][nt][rg] + bb;
                    if (RELU) x = x > 0.f ? x : 0.f;
                    if (OUT_DUAL && !isbf)
                        ((float*)outp)[(size_t)gr * 128 + col] = x;
                    else
                        ((unsigned short*)outp)[(size_t)gr * 128 + col] = f2b(x);
                }
            }
        }
    }
}

// ---------------------------------------------------------------------------
extern "C" void kernel_launch(void* const* d_in, const int* in_sizes, int n_in,
                              void* d_out, int out_size, void* d_ws, size_t ws_size,
                              hipStream_t stream) {
    const void* node_feats  = d_in[0];
    const void* edge_logits = d_in[1];
    const void* W_proj      = d_in[2];
    const void* b_proj      = d_in[3];
    const void* W1          = d_in[4];
    const void* b1          = d_in[5];
    const void* W2          = d_in[6];
    const void* b2          = d_in[7];
    const int*  src         = (const int*)d_in[8];
    const int*  dst         = (const int*)d_in[9];

    const int N = in_sizes[0] / 128;
    const int E = in_sizes[8];
    const int NB = (N + BUCKET_NODES - 1) / BUCKET_NODES;   // <= 1024

    char* ws = (char*)d_ws;
    size_t off = 0;
    unsigned short* hv    = (unsigned short*)(ws + off); off += (size_t)N * 256;
    unsigned short* ctx   = (unsigned short*)(ws + off); off += (size_t)N * 256;
    unsigned short* h_buf = (unsigned short*)(ws + off); off += (size_t)N * 256;
    uint2* ebuf = (uint2*)(ws + off); off += (size_t)E * 8;
    unsigned short* Wtp = (unsigned short*)(ws + off); off += 128 * 128 * 2;
    unsigned short* Wt1 = (unsigned short*)(ws + off); off += 128 * 256 * 2;
    unsigned short* Wt2 = (unsigned short*)(ws + off); off += 128 * 128 * 2;
    int* bcount  = (int*)(ws + off); off += MAX_NB * 4;
    int* bstart  = (int*)(ws + off); off += MAX_NB * 4;
    int* bcursor = (int*)(ws + off); off += MAX_NB * 4;
    int* flag    = (int*)(ws + off);

    const int gblocks = (N + 127) / 128;
    const int ebblocks = (E + 8191) / 8192;

    detect_kernel<<<1, 64, 0, stream>>>((const unsigned int*)node_feats, flag);
    hipMemsetAsync(bcount, 0, MAX_NB * 4, stream);

    transpose_w_kernel<<<(128 * 128 + 255) / 256, 256, 0, stream>>>(W_proj, Wtp, flag, 128);
    transpose_w_kernel<<<(128 * 256 + 255) / 256, 256, 0, stream>>>(W1, Wt1, flag, 256);
    transpose_w_kernel<<<(128 * 128 + 255) / 256, 256, 0, stream>>>(W2, Wt2, flag, 128);

    bhist_kernel<<<ebblocks, 256, 0, stream>>>(dst, bcount, E);
    bscan_kernel<<<1, 256, 0, stream>>>(bcount, bstart, bcursor, NB);
    bappend_kernel<<<ebblocks, 256, 0, stream>>>(dst, src, edge_logits, bcursor,
                                                 ebuf, flag, E);

    gemm_mfma<128, 0, false, true, false><<<gblocks, 256, 0, stream>>>(
        node_feats, nullptr, Wtp, b_proj, hv, flag, N);

    agg_fused_kernel<<<NB, 256, 0, stream>>>(ebuf, bstart, bcount,
                                             (const unsigned int*)hv,
                                             (unsigned int*)ctx, N);

    gemm_mfma<256, 1, true, true, false><<<gblocks, 256, 0, stream>>>(
        node_feats, ctx, Wt1, b1, h_buf, flag, N);
    gemm_mfma<128, 0, true, false, true><<<gblocks, 256, 0, stream>>>(
        h_buf, nullptr, Wt2, b2, d_out, flag, N);
}

// Round 6
// 381.098 us; speedup vs baseline: 4.3396x; 4.3396x over previous
//
#include <hip/hip_runtime.h>
#include <hip/hip_bf16.h>

typedef __hip_bfloat16 bf16;
typedef __attribute__((ext_vector_type(8))) __bf16 bf16x8;
typedef __attribute__((ext_vector_type(4))) float floatx4;

#define BUCKET_SHIFT 7
#define BUCKET_NODES 128
#define MAX_NB 1024

__device__ __forceinline__ unsigned short f2b(float f) {
    bf16 h = __float2bfloat16(f);
    unsigned short s;
    __builtin_memcpy(&s, &h, 2);
    return s;
}
__device__ __forceinline__ float b2f(unsigned short u) {
    unsigned int x = ((unsigned int)u) << 16;
    float f;
    __builtin_memcpy(&f, &x, 4);
    return f;
}
__device__ __forceinline__ float load_dual(const void* p, long long i, bool isbf) {
    return isbf ? b2f(((const unsigned short*)p)[i]) : ((const float*)p)[i];
}
__device__ __forceinline__ bf16x8 ldsfrag(const unsigned short* p) {
    union { uint4 u; bf16x8 v; } t;
    t.u = *(const uint4*)p;
    return t.v;
}

// ---------------------------------------------------------------------------
// Dtype detection: flag=1 if float arrays are bf16-packed, 0 if true f32.
// ---------------------------------------------------------------------------
__global__ __launch_bounds__(64) void detect_kernel(const unsigned int* __restrict__ words,
                                                    int* __restrict__ flag) {
    int cnt = 0;
    for (int i = threadIdx.x; i < 4096; i += 64) {
        unsigned int lo = words[i] & 0xFFFFu;
        unsigned int e = (lo >> 7) & 0xFFu;
        if (lo == 0u || (e >= 110u && e <= 135u)) cnt++;
    }
#pragma unroll
    for (int off = 32; off > 0; off >>= 1) cnt += __shfl_down(cnt, off, 64);
    if (threadIdx.x == 0) *flag = (cnt > 2458) ? 1 : 0;
}

// ---------------------------------------------------------------------------
// W[K][128] (dual) -> Wt bf16-bits [128][K]
// ---------------------------------------------------------------------------
__global__ __launch_bounds__(256) void transpose_w_kernel(const void* __restrict__ W,
                                                          unsigned short* __restrict__ Wt,
                                                          const int* __restrict__ flag, int K) {
    bool isbf = (*flag != 0);
    int idx = blockIdx.x * 256 + threadIdx.x;
    if (idx >= 128 * K) return;
    int n = idx / K, k = idx - n * K;
    Wt[idx] = f2b(load_dual(W, (long long)k * 128 + n, isbf));
}

// ---------------------------------------------------------------------------
// Bucket histogram (LDS-aggregated): bcount[dst>>7]++, 8192 edges/block.
// ---------------------------------------------------------------------------
__global__ __launch_bounds__(256) void bhist_kernel(const int* __restrict__ dst,
                                                    int* __restrict__ bcount, int E) {
    __shared__ int lcnt[MAX_NB];
    for (int i = threadIdx.x; i < MAX_NB; i += 256) lcnt[i] = 0;
    __syncthreads();
    int base = blockIdx.x * 8192;
#pragma unroll
    for (int j = 0; j < 32; ++j) {
        int e = base + j * 256 + threadIdx.x;
        if (e < E) atomicAdd(&lcnt[dst[e] >> BUCKET_SHIFT], 1);
    }
    __syncthreads();
    for (int i = threadIdx.x; i < MAX_NB; i += 256)
        if (lcnt[i]) atomicAdd(&bcount[i], lcnt[i]);
}

// ---------------------------------------------------------------------------
// Single-block exclusive scan of bucket counts (NB <= 1024) -> bstart, bcursor
// ---------------------------------------------------------------------------
__global__ __launch_bounds__(256) void bscan_kernel(const int* __restrict__ bcount,
                                                    int* __restrict__ bstart,
                                                    int* __restrict__ bcursor, int NB) {
    int t = threadIdx.x;
    int v[4];
    int sum = 0;
#pragma unroll
    for (int j = 0; j < 4; ++j) {
        int i = t * 4 + j;
        v[j] = (i < NB) ? bcount[i] : 0;
        sum += v[j];
    }
    int lane = t & 63, wave = t >> 6;
    int inc = sum;
#pragma unroll
    for (int off = 1; off < 64; off <<= 1) {
        int x = __shfl_up(inc, off, 64);
        if (lane >= off) inc += x;
    }
    __shared__ int wsum[4];
    if (lane == 63) wsum[wave] = inc;
    __syncthreads();
    int woff = 0;
    for (int w = 0; w < wave; ++w) woff += wsum[w];
    int run = inc - sum + woff;
#pragma unroll
    for (int j = 0; j < 4; ++j) {
        int i = t * 4 + j;
        if (i < NB) { bstart[i] = run; bcursor[i] = run; }
        run += v[j];
    }
}

// ---------------------------------------------------------------------------
// Bucket append: records { src | dstLocal<<24, bits(exp(logit)) } into dense
// per-bucket regions via per-block LDS chunk reservation (low write amp).
// ---------------------------------------------------------------------------
__global__ __launch_bounds__(256) void bappend_kernel(const int* __restrict__ dst,
                                                      const int* __restrict__ src,
                                                      const void* __restrict__ logits,
                                                      int* __restrict__ bcursor,
                                                      uint2* __restrict__ ebuf,
                                                      const int* __restrict__ flag, int E) {
    __shared__ int lcnt[MAX_NB];
    __shared__ int lbase[MAX_NB];
    for (int i = threadIdx.x; i < MAX_NB; i += 256) lcnt[i] = 0;
    __syncthreads();
    const bool isbf = (*flag != 0);
    int base = blockIdx.x * 8192;
#pragma unroll
    for (int j = 0; j < 32; ++j) {
        int e = base + j * 256 + threadIdx.x;
        if (e < E) atomicAdd(&lcnt[dst[e] >> BUCKET_SHIFT], 1);
    }
    __syncthreads();
    for (int i = threadIdx.x; i < MAX_NB; i += 256) {
        int c = lcnt[i];
        if (c) { lbase[i] = atomicAdd(&bcursor[i], c); lcnt[i] = 0; }
    }
    __syncthreads();
#pragma unroll
    for (int j = 0; j < 32; ++j) {
        int e = base + j * 256 + threadIdx.x;
        if (e < E) {
            int d = dst[e];
            int b = d >> BUCKET_SHIFT;
            float w = expf(load_dual(logits, e, isbf));
            int pos = lbase[b] + atomicAdd(&lcnt[b], 1);
            uint2 rec;
            rec.x = (unsigned int)src[e] | ((unsigned int)(d & (BUCKET_NODES - 1)) << 24);
            rec.y = __float_as_uint(w);
            ebuf[pos] = rec;
        }
    }
}

// ---------------------------------------------------------------------------
// Bucket-local CSR: one block per bucket. Count per local node (LDS), scan,
// scatter node-sorted records into ebuf2 (contiguous ~16KB window -> L2
// absorbs the in-window randomness). Emits row_start/ncount per node.
// ---------------------------------------------------------------------------
__global__ __launch_bounds__(256) void bcsr_kernel(const uint2* __restrict__ ebuf,
                                                   const int* __restrict__ bstart,
                                                   const int* __restrict__ bcount,
                                                   uint2* __restrict__ ebuf2,
                                                   int* __restrict__ row_start,
                                                   int* __restrict__ ncount, int N) {
    __shared__ int lcnt[BUCKET_NODES];
    __shared__ int lbase[BUCKET_NODES];
    const int b = blockIdx.x;
    const int s0 = bstart[b];
    const int cnt = bcount[b];
    if (threadIdx.x < BUCKET_NODES) lcnt[threadIdx.x] = 0;
    __syncthreads();
    for (int i = threadIdx.x; i < cnt; i += 256)
        atomicAdd(&lcnt[ebuf[s0 + i].x >> 24], 1);
    __syncthreads();
    // exclusive scan of 128 counters by wave 0 (2 x 64-lane shfl scan)
    if (threadIdx.x < 64) {
        int lane = threadIdx.x;
        int carry = 0;
#pragma unroll
        for (int half = 0; half < 2; ++half) {
            int idx = half * 64 + lane;
            int v = lcnt[idx];
            int inc = v;
#pragma unroll
            for (int off = 1; off < 64; off <<= 1) {
                int t = __shfl_up(inc, off, 64);
                if (lane >= off) inc += t;
            }
            lbase[idx] = carry + inc - v;
            carry += __shfl(inc, 63, 64);
        }
    }
    __syncthreads();
    if (threadIdx.x < BUCKET_NODES) {
        int gn = b * BUCKET_NODES + threadIdx.x;
        if (gn < N) {
            row_start[gn] = s0 + lbase[threadIdx.x];
            ncount[gn] = lcnt[threadIdx.x];
        }
    }
    __syncthreads();                 // lcnt reads done before reset
    if (threadIdx.x < BUCKET_NODES) lcnt[threadIdx.x] = 0;
    __syncthreads();
    for (int i = threadIdx.x; i < cnt; i += 256) {
        uint2 rec = ebuf[s0 + i];
        int dl = rec.x >> 24;
        int pos = lbase[dl] + atomicAdd(&lcnt[dl], 1);
        ebuf2[s0 + pos] = make_uint2(rec.x & 0xFFFFFFu, rec.y);
    }
}

// ---------------------------------------------------------------------------
// Aggregation: one wave/node, 2 features/lane, register accumulation, 8-wide
// unroll (8 independent hv gathers in flight). ctx = elu(acc/z) bf16.
// ---------------------------------------------------------------------------
__global__ __launch_bounds__(256) void agg_csr_kernel(const int* __restrict__ row_start,
                                                      const int* __restrict__ ncount,
                                                      const uint2* __restrict__ erec,
                                                      const unsigned int* __restrict__ hv32,
                                                      unsigned int* __restrict__ ctx32, int N) {
    int n = blockIdx.x * 4 + (threadIdx.x >> 6);
    int lane = threadIdx.x & 63;
    if (n >= N) return;
    int s0 = row_start[n];
    int deg = ncount[n];
    float accx = 0.f, accy = 0.f, z = 0.f;
    int i = 0;
    for (; i + 8 <= deg; i += 8) {
        uint2 r[8];
        unsigned int h[8];
#pragma unroll
        for (int j = 0; j < 8; ++j) r[j] = erec[s0 + i + j];
#pragma unroll
        for (int j = 0; j < 8; ++j) h[j] = hv32[(size_t)r[j].x * 64 + lane];
#pragma unroll
        for (int j = 0; j < 8; ++j) {
            float w = __uint_as_float(r[j].y);
            z += w;
            accx += w * b2f((unsigned short)h[j]);
            accy += w * b2f((unsigned short)(h[j] >> 16));
        }
    }
    for (; i + 4 <= deg; i += 4) {
        uint2 r[4];
        unsigned int h[4];
#pragma unroll
        for (int j = 0; j < 4; ++j) r[j] = erec[s0 + i + j];
#pragma unroll
        for (int j = 0; j < 4; ++j) h[j] = hv32[(size_t)r[j].x * 64 + lane];
#pragma unroll
        for (int j = 0; j < 4; ++j) {
            float w = __uint_as_float(r[j].y);
            z += w;
            accx += w * b2f((unsigned short)h[j]);
            accy += w * b2f((unsigned short)(h[j] >> 16));
        }
    }
    for (; i < deg; ++i) {
        uint2 r = erec[s0 + i];
        unsigned int h = hv32[(size_t)r.x * 64 + lane];
        float w = __uint_as_float(r.y);
        z += w;
        accx += w * b2f((unsigned short)h);
        accy += w * b2f((unsigned short)(h >> 16));
    }
    float rz = (z > 0.f) ? 1.f / z : 0.f;
    float x = accx * rz, y = accy * rz;
    x = x > 0.f ? x : expm1f(x);
    y = y > 0.f ? y : expm1f(y);
    ctx32[(size_t)n * 64 + lane] = ((unsigned int)f2b(y) << 16) | f2b(x);
}

// ---------------------------------------------------------------------------
// MFMA GEMM: out[N,128] = act( A[N,K] @ W[K,128] + b ), W given as Wt[128][K].
// Block: 128 rows x 128 cols, 4 waves; wave = 2x8 tiles of 16x16, K-chunk 64.
// MODE 1: A = concat(ctx bf16 [N,128], A [N,128]), K=256.
// ---------------------------------------------------------------------------
template <int K, int MODE, bool RELU, bool A_DUAL, bool OUT_DUAL>
__global__ __launch_bounds__(256) void gemm_mfma(const void* __restrict__ A,
                                                 const unsigned short* __restrict__ Actx,
                                                 const unsigned short* __restrict__ Wt,
                                                 const void* __restrict__ bias,
                                                 void* __restrict__ outp,
                                                 const int* __restrict__ flag, int N) {
    __shared__ unsigned short Alds[128 * 72];
    __shared__ unsigned short Wlds[128 * 72];
    const bool isbf = (*flag != 0);
    const int t = threadIdx.x;
    const int wid = t >> 6;
    const int lane = t & 63;
    const int m16 = lane & 15;
    const int quad = lane >> 4;
    const int row0 = blockIdx.x * 128;

    floatx4 acc[2][8];
#pragma unroll
    for (int i = 0; i < 2; ++i)
#pragma unroll
        for (int j = 0; j < 8; ++j) acc[i][j] = (floatx4){0.f, 0.f, 0.f, 0.f};

    const int r  = t >> 1;
    const int kh = (t & 1) * 32;

#pragma unroll
    for (int kc = 0; kc < K / 64; ++kc) {
        {
            const unsigned short* wp = Wt + (size_t)r * K + kc * 64 + kh;
            uint4* o = (uint4*)&Wlds[r * 72 + kh];
            o[0] = ((const uint4*)wp)[0];
            o[1] = ((const uint4*)wp)[1];
            o[2] = ((const uint4*)wp)[2];
            o[3] = ((const uint4*)wp)[3];
        }
        {
            int grow = row0 + r;
            if (grow >= N) grow = N - 1;
            uint4* o = (uint4*)&Alds[r * 72 + kh];
            if (MODE == 1 && kc < 2) {
                const unsigned short* ap = Actx + (size_t)grow * 128 + kc * 64 + kh;
                o[0] = ((const uint4*)ap)[0];
                o[1] = ((const uint4*)ap)[1];
                o[2] = ((const uint4*)ap)[2];
                o[3] = ((const uint4*)ap)[3];
            } else {
                const int stride = (MODE == 1) ? 128 : K;
                const int kabs = (MODE == 1) ? (kc * 64 - 128 + kh) : (kc * 64 + kh);
                if (A_DUAL && !isbf) {
                    const float* ap = (const float*)A + (size_t)grow * stride + kabs;
#pragma unroll
                    for (int q = 0; q < 4; ++q) {
                        float4 v0 = ((const float4*)ap)[2 * q];
                        float4 v1 = ((const float4*)ap)[2 * q + 1];
                        union { uint4 u; unsigned short s[8]; } P;
                        P.s[0] = f2b(v0.x); P.s[1] = f2b(v0.y);
                        P.s[2] = f2b(v0.z); P.s[3] = f2b(v0.w);
                        P.s[4] = f2b(v1.x); P.s[5] = f2b(v1.y);
                        P.s[6] = f2b(v1.z); P.s[7] = f2b(v1.w);
                        o[q] = P.u;
                    }
                } else {
                    const unsigned short* ap = (const unsigned short*)A + (size_t)grow * stride + kabs;
                    o[0] = ((const uint4*)ap)[0];
                    o[1] = ((const uint4*)ap)[1];
                    o[2] = ((const uint4*)ap)[2];
                    o[3] = ((const uint4*)ap)[3];
                }
            }
        }
        __syncthreads();

#pragma unroll
        for (int c = 0; c < 2; ++c) {
            const int ko = c * 32 + quad * 8;
            bf16x8 a0 = ldsfrag(&Alds[(wid * 32 + m16) * 72 + ko]);
            bf16x8 a1 = ldsfrag(&Alds[(wid * 32 + 16 + m16) * 72 + ko]);
#pragma unroll
            for (int nt = 0; nt < 8; ++nt) {
                bf16x8 bb = ldsfrag(&Wlds[(nt * 16 + m16) * 72 + ko]);
                acc[0][nt] = __builtin_amdgcn_mfma_f32_16x16x32_bf16(a0, bb, acc[0][nt], 0, 0, 0);
                acc[1][nt] = __builtin_amdgcn_mfma_f32_16x16x32_bf16(a1, bb, acc[1][nt], 0, 0, 0);
            }
        }
        __syncthreads();
    }

#pragma unroll
    for (int mt = 0; mt < 2; ++mt) {
        int gr0 = row0 + wid * 32 + mt * 16 + quad * 4;
#pragma unroll
        for (int nt = 0; nt < 8; ++nt) {
            int col = nt * 16 + m16;
            float bb = load_dual(bias, col, isbf);
#pragma unroll
            for (int rg = 0; rg < 4; ++rg) {
                int gr = gr0 + rg;
                if (gr < N) {
                    float x = acc[mt][nt][rg] + bb;
                    if (RELU) x = x > 0.f ? x : 0.f;
                    if (OUT_DUAL && !isbf)
                        ((float*)outp)[(size_t)gr * 128 + col] = x;
                    else
                        ((unsigned short*)outp)[(size_t)gr * 128 + col] = f2b(x);
                }
            }
        }
    }
}

// ---------------------------------------------------------------------------
extern "C" void kernel_launch(void* const* d_in, const int* in_sizes, int n_in,
                              void* d_out, int out_size, void* d_ws, size_t ws_size,
                              hipStream_t stream) {
    const void* node_feats  = d_in[0];
    const void* edge_logits = d_in[1];
    const void* W_proj      = d_in[2];
    const void* b_proj      = d_in[3];
    const void* W1          = d_in[4];
    const void* b1          = d_in[5];
    const void* W2          = d_in[6];
    const void* b2          = d_in[7];
    const int*  src         = (const int*)d_in[8];
    const int*  dst         = (const int*)d_in[9];

    const int N = in_sizes[0] / 128;
    const int E = in_sizes[8];
    const int NB = (N + BUCKET_NODES - 1) / BUCKET_NODES;   // <= 1024

    char* ws = (char*)d_ws;
    size_t off = 0;
    unsigned short* hv    = (unsigned short*)(ws + off); off += (size_t)N * 256;
    unsigned short* ctx   = (unsigned short*)(ws + off); off += (size_t)N * 256;
    unsigned short* h_buf = (unsigned short*)(ws + off); off += (size_t)N * 256;
    uint2* ebuf  = (uint2*)(ws + off); off += (size_t)E * 8;
    uint2* ebuf2 = (uint2*)(ws + off); off += (size_t)E * 8;
    unsigned short* Wtp = (unsigned short*)(ws + off); off += 128 * 128 * 2;
    unsigned short* Wt1 = (unsigned short*)(ws + off); off += 128 * 256 * 2;
    unsigned short* Wt2 = (unsigned short*)(ws + off); off += 128 * 128 * 2;
    int* bcount    = (int*)(ws + off); off += MAX_NB * 4;
    int* bstart    = (int*)(ws + off); off += MAX_NB * 4;
    int* bcursor   = (int*)(ws + off); off += MAX_NB * 4;
    int* row_start = (int*)(ws + off); off += (size_t)N * 4;
    int* ncount    = (int*)(ws + off); off += (size_t)N * 4;
    int* flag      = (int*)(ws + off);

    const int gblocks = (N + 127) / 128;
    const int ebblocks = (E + 8191) / 8192;

    detect_kernel<<<1, 64, 0, stream>>>((const unsigned int*)node_feats, flag);
    hipMemsetAsync(bcount, 0, MAX_NB * 4, stream);

    transpose_w_kernel<<<(128 * 128 + 255) / 256, 256, 0, stream>>>(W_proj, Wtp, flag, 128);
    transpose_w_kernel<<<(128 * 256 + 255) / 256, 256, 0, stream>>>(W1, Wt1, flag, 256);
    transpose_w_kernel<<<(128 * 128 + 255) / 256, 256, 0, stream>>>(W2, Wt2, flag, 128);

    bhist_kernel<<<ebblocks, 256, 0, stream>>>(dst, bcount, E);
    bscan_kernel<<<1, 256, 0, stream>>>(bcount, bstart, bcursor, NB);
    bappend_kernel<<<ebblocks, 256, 0, stream>>>(dst, src, edge_logits, bcursor,
                                                 ebuf, flag, E);
    bcsr_kernel<<<NB, 256, 0, stream>>>(ebuf, bstart, bcount, ebuf2,
                                        row_start, ncount, N);

    gemm_mfma<128, 0, false, true, false><<<gblocks, 256, 0, stream>>>(
        node_feats, nullptr, Wtp, b_proj, hv, flag, N);

    agg_csr_kernel<<<(N + 3) / 4, 256, 0, stream>>>(row_start, ncount, ebuf2,
                                                    (const unsigned int*)hv,
                                                    (unsigned int*)ctx, N);

    gemm_mfma<256, 1, true, true, false><<<gblocks, 256, 0, stream>>>(
        node_feats, ctx, Wt1, b1, h_buf, flag, N);
    gemm_mfma<128, 0, true, false, true><<<gblocks, 256, 0, stream>>>(
        h_buf, nullptr, Wt2, b2, d_out, flag, N);
}

// Round 7
// 350.848 us; speedup vs baseline: 4.7137x; 1.0862x over previous
//
#include <hip/hip_runtime.h>
#include <hip/hip_bf16.h>

typedef __hip_bfloat16 bf16;
typedef __attribute__((ext_vector_type(8))) __bf16 bf16x8;
typedef __attribute__((ext_vector_type(4))) float floatx4;

#define BUCKET_SHIFT 7
#define BUCKET_NODES 128
#define MAX_NB 1024

__device__ __forceinline__ unsigned short f2b(float f) {
    bf16 h = __float2bfloat16(f);
    unsigned short s;
    __builtin_memcpy(&s, &h, 2);
    return s;
}
__device__ __forceinline__ float b2f(unsigned short u) {
    unsigned int x = ((unsigned int)u) << 16;
    float f;
    __builtin_memcpy(&f, &x, 4);
    return f;
}
__device__ __forceinline__ float load_dual(const void* p, long long i, bool isbf) {
    return isbf ? b2f(((const unsigned short*)p)[i]) : ((const float*)p)[i];
}
__device__ __forceinline__ bf16x8 ldsfrag(const unsigned short* p) {
    union { uint4 u; bf16x8 v; } t;
    t.u = *(const uint4*)p;
    return t.v;
}
// 8 bf16 A-fragment from a dual-dtype [rows][stride] matrix, row-major
__device__ __forceinline__ bf16x8 gfrag_dual(const void* A, int row, int stride, int k0, bool isbf) {
    if (isbf) {
        union { uint4 u; bf16x8 v; } t;
        t.u = *(const uint4*)((const unsigned short*)A + (size_t)row * stride + k0);
        return t.v;
    }
    const float* ap = (const float*)A + (size_t)row * stride + k0;
    float4 v0 = ((const float4*)ap)[0];
    float4 v1 = ((const float4*)ap)[1];
    union { unsigned short s[8]; bf16x8 v; } t;
    t.s[0] = f2b(v0.x); t.s[1] = f2b(v0.y); t.s[2] = f2b(v0.z); t.s[3] = f2b(v0.w);
    t.s[4] = f2b(v1.x); t.s[5] = f2b(v1.y); t.s[6] = f2b(v1.z); t.s[7] = f2b(v1.w);
    return t.v;
}

// ---------------------------------------------------------------------------
// Dtype detection: flag=1 if float arrays are bf16-packed, 0 if true f32.
// ---------------------------------------------------------------------------
__global__ __launch_bounds__(64) void detect_kernel(const unsigned int* __restrict__ words,
                                                    int* __restrict__ flag) {
    int cnt = 0;
    for (int i = threadIdx.x; i < 4096; i += 64) {
        unsigned int lo = words[i] & 0xFFFFu;
        unsigned int e = (lo >> 7) & 0xFFu;
        if (lo == 0u || (e >= 110u && e <= 135u)) cnt++;
    }
#pragma unroll
    for (int off = 32; off > 0; off >>= 1) cnt += __shfl_down(cnt, off, 64);
    if (threadIdx.x == 0) *flag = (cnt > 2458) ? 1 : 0;
}

// ---------------------------------------------------------------------------
// All three weight transposes in one kernel: Wt[n][k] = W[k][n] (bf16 bits)
// ---------------------------------------------------------------------------
__global__ __launch_bounds__(256) void transpose_all_kernel(const void* __restrict__ Wp,
                                                            const void* __restrict__ W1,
                                                            const void* __restrict__ W2,
                                                            unsigned short* __restrict__ Wtp,
                                                            unsigned short* __restrict__ Wt1,
                                                            unsigned short* __restrict__ Wt2,
                                                            const int* __restrict__ flag) {
    bool isbf = (*flag != 0);
    int idx = blockIdx.x * 256 + threadIdx.x;
    if (idx < 16384) {
        int n = idx >> 7, k = idx & 127;
        Wtp[idx] = f2b(load_dual(Wp, (long long)k * 128 + n, isbf));
    } else if (idx < 49152) {
        int j = idx - 16384;
        int n = j >> 8, k = j & 255;
        Wt1[j] = f2b(load_dual(W1, (long long)k * 128 + n, isbf));
    } else if (idx < 65536) {
        int j = idx - 49152;
        int n = j >> 7, k = j & 127;
        Wt2[j] = f2b(load_dual(W2, (long long)k * 128 + n, isbf));
    }
}

// ---------------------------------------------------------------------------
// Bucket histogram (LDS-aggregated): bcount[dst>>7]++, 8192 edges/block.
// ---------------------------------------------------------------------------
__global__ __launch_bounds__(256) void bhist_kernel(const int* __restrict__ dst,
                                                    int* __restrict__ bcount, int E) {
    __shared__ int lcnt[MAX_NB];
    for (int i = threadIdx.x; i < MAX_NB; i += 256) lcnt[i] = 0;
    __syncthreads();
    int base = blockIdx.x * 8192;
#pragma unroll
    for (int j = 0; j < 32; ++j) {
        int e = base + j * 256 + threadIdx.x;
        if (e < E) atomicAdd(&lcnt[dst[e] >> BUCKET_SHIFT], 1);
    }
    __syncthreads();
    for (int i = threadIdx.x; i < MAX_NB; i += 256)
        if (lcnt[i]) atomicAdd(&bcount[i], lcnt[i]);
}

// ---------------------------------------------------------------------------
// Single-block exclusive scan of bucket counts (NB <= 1024) -> bstart, bcursor
// ---------------------------------------------------------------------------
__global__ __launch_bounds__(256) void bscan_kernel(const int* __restrict__ bcount,
                                                    int* __restrict__ bstart,
                                                    int* __restrict__ bcursor, int NB) {
    int t = threadIdx.x;
    int v[4];
    int sum = 0;
#pragma unroll
    for (int j = 0; j < 4; ++j) {
        int i = t * 4 + j;
        v[j] = (i < NB) ? bcount[i] : 0;
        sum += v[j];
    }
    int lane = t & 63, wave = t >> 6;
    int inc = sum;
#pragma unroll
    for (int off = 1; off < 64; off <<= 1) {
        int x = __shfl_up(inc, off, 64);
        if (lane >= off) inc += x;
    }
    __shared__ int wsum[4];
    if (lane == 63) wsum[wave] = inc;
    __syncthreads();
    int woff = 0;
    for (int w = 0; w < wave; ++w) woff += wsum[w];
    int run = inc - sum + woff;
#pragma unroll
    for (int j = 0; j < 4; ++j) {
        int i = t * 4 + j;
        if (i < NB) { bstart[i] = run; bcursor[i] = run; }
        run += v[j];
    }
}

// ---------------------------------------------------------------------------
// Bucket append: records { src | dstLocal<<24, bits(exp(logit)) } into dense
// per-bucket regions via per-block LDS chunk reservation (low write amp).
// ---------------------------------------------------------------------------
__global__ __launch_bounds__(256) void bappend_kernel(const int* __restrict__ dst,
                                                      const int* __restrict__ src,
                                                      const void* __restrict__ logits,
                                                      int* __restrict__ bcursor,
                                                      uint2* __restrict__ ebuf,
                                                      const int* __restrict__ flag, int E) {
    __shared__ int lcnt[MAX_NB];
    __shared__ int lbase[MAX_NB];
    for (int i = threadIdx.x; i < MAX_NB; i += 256) lcnt[i] = 0;
    __syncthreads();
    const bool isbf = (*flag != 0);
    int base = blockIdx.x * 8192;
#pragma unroll
    for (int j = 0; j < 32; ++j) {
        int e = base + j * 256 + threadIdx.x;
        if (e < E) atomicAdd(&lcnt[dst[e] >> BUCKET_SHIFT], 1);
    }
    __syncthreads();
    for (int i = threadIdx.x; i < MAX_NB; i += 256) {
        int c = lcnt[i];
        if (c) { lbase[i] = atomicAdd(&bcursor[i], c); lcnt[i] = 0; }
    }
    __syncthreads();
#pragma unroll
    for (int j = 0; j < 32; ++j) {
        int e = base + j * 256 + threadIdx.x;
        if (e < E) {
            int d = dst[e];
            int b = d >> BUCKET_SHIFT;
            float w = expf(load_dual(logits, e, isbf));
            int pos = lbase[b] + atomicAdd(&lcnt[b], 1);
            uint2 rec;
            rec.x = (unsigned int)src[e] | ((unsigned int)(d & (BUCKET_NODES - 1)) << 24);
            rec.y = __float_as_uint(w);
            ebuf[pos] = rec;
        }
    }
}

// ---------------------------------------------------------------------------
// Bucket-local CSR: one block per bucket; count/scan/scatter node-sorted
// records into a contiguous 16KB window. Emits row_start/ncount per node.
// ---------------------------------------------------------------------------
__global__ __launch_bounds__(256) void bcsr_kernel(const uint2* __restrict__ ebuf,
                                                   const int* __restrict__ bstart,
                                                   const int* __restrict__ bcount,
                                                   uint2* __restrict__ ebuf2,
                                                   int* __restrict__ row_start,
                                                   int* __restrict__ ncount, int N) {
    __shared__ int lcnt[BUCKET_NODES];
    __shared__ int lbase[BUCKET_NODES];
    const int b = blockIdx.x;
    const int s0 = bstart[b];
    const int cnt = bcount[b];
    if (threadIdx.x < BUCKET_NODES) lcnt[threadIdx.x] = 0;
    __syncthreads();
    for (int i = threadIdx.x; i < cnt; i += 256)
        atomicAdd(&lcnt[ebuf[s0 + i].x >> 24], 1);
    __syncthreads();
    if (threadIdx.x < 64) {
        int lane = threadIdx.x;
        int carry = 0;
#pragma unroll
        for (int half = 0; half < 2; ++half) {
            int idx = half * 64 + lane;
            int v = lcnt[idx];
            int inc = v;
#pragma unroll
            for (int off = 1; off < 64; off <<= 1) {
                int t = __shfl_up(inc, off, 64);
                if (lane >= off) inc += t;
            }
            lbase[idx] = carry + inc - v;
            carry += __shfl(inc, 63, 64);
        }
    }
    __syncthreads();
    if (threadIdx.x < BUCKET_NODES) {
        int gn = b * BUCKET_NODES + threadIdx.x;
        if (gn < N) {
            row_start[gn] = s0 + lbase[threadIdx.x];
            ncount[gn] = lcnt[threadIdx.x];
        }
    }
    __syncthreads();
    if (threadIdx.x < BUCKET_NODES) lcnt[threadIdx.x] = 0;
    __syncthreads();
    for (int i = threadIdx.x; i < cnt; i += 256) {
        uint2 rec = ebuf[s0 + i];
        int dl = rec.x >> 24;
        int pos = lbase[dl] + atomicAdd(&lcnt[dl], 1);
        ebuf2[s0 + pos] = make_uint2(rec.x & 0xFFFFFFu, rec.y);
    }
}

// ---------------------------------------------------------------------------
// Aggregation: one wave/node, 2 features/lane, register accumulation, 8-wide
// unroll (8 independent hv gathers in flight). ctx = elu(acc/z) bf16.
// ---------------------------------------------------------------------------
__global__ __launch_bounds__(256) void agg_csr_kernel(const int* __restrict__ row_start,
                                                      const int* __restrict__ ncount,
                                                      const uint2* __restrict__ erec,
                                                      const unsigned int* __restrict__ hv32,
                                                      unsigned int* __restrict__ ctx32, int N) {
    int n = blockIdx.x * 4 + (threadIdx.x >> 6);
    int lane = threadIdx.x & 63;
    if (n >= N) return;
    int s0 = row_start[n];
    int deg = ncount[n];
    float accx = 0.f, accy = 0.f, z = 0.f;
    int i = 0;
    for (; i + 8 <= deg; i += 8) {
        uint2 r[8];
        unsigned int h[8];
#pragma unroll
        for (int j = 0; j < 8; ++j) r[j] = erec[s0 + i + j];
#pragma unroll
        for (int j = 0; j < 8; ++j) h[j] = hv32[(size_t)r[j].x * 64 + lane];
#pragma unroll
        for (int j = 0; j < 8; ++j) {
            float w = __uint_as_float(r[j].y);
            z += w;
            accx += w * b2f((unsigned short)h[j]);
            accy += w * b2f((unsigned short)(h[j] >> 16));
        }
    }
    for (; i + 4 <= deg; i += 4) {
        uint2 r[4];
        unsigned int h[4];
#pragma unroll
        for (int j = 0; j < 4; ++j) r[j] = erec[s0 + i + j];
#pragma unroll
        for (int j = 0; j < 4; ++j) h[j] = hv32[(size_t)r[j].x * 64 + lane];
#pragma unroll
        for (int j = 0; j < 4; ++j) {
            float w = __uint_as_float(r[j].y);
            z += w;
            accx += w * b2f((unsigned short)h[j]);
            accy += w * b2f((unsigned short)(h[j] >> 16));
        }
    }
    for (; i < deg; ++i) {
        uint2 r = erec[s0 + i];
        unsigned int h = hv32[(size_t)r.x * 64 + lane];
        float w = __uint_as_float(r.y);
        z += w;
        accx += w * b2f((unsigned short)h);
        accy += w * b2f((unsigned short)(h >> 16));
    }
    float rz = (z > 0.f) ? 1.f / z : 0.f;
    float x = accx * rz, y = accy * rz;
    x = x > 0.f ? x : expm1f(x);
    y = y > 0.f ? y : expm1f(y);
    ctx32[(size_t)n * 64 + lane] = ((unsigned int)f2b(y) << 16) | f2b(x);
}

// ---------------------------------------------------------------------------
// Projection GEMM (W-in-LDS, A-direct): hv = nf @ Wp + bp, bf16 out.
// 128x128 block, 4 waves, wave = 2x8 16x16 tiles. Whole Wt staged once;
// K-loop is barrier-free (A-frags straight from global, coalesced).
// ---------------------------------------------------------------------------
__global__ __launch_bounds__(256) void gemm_proj(const void* __restrict__ A,
                                                 const unsigned short* __restrict__ Wt,
                                                 const void* __restrict__ bias,
                                                 unsigned short* __restrict__ hv,
                                                 const int* __restrict__ flag, int N) {
    __shared__ unsigned short Wl[128 * 136];
    const bool isbf = (*flag != 0);
    const int t = threadIdx.x, wid = t >> 6, lane = t & 63;
    const int m16 = lane & 15, quad = lane >> 4;
    const int row0 = blockIdx.x * 128;
    {
        int r = t >> 1, kh = (t & 1) * 64;
        const uint4* s = (const uint4*)(Wt + (size_t)r * 128 + kh);
        uint4* d = (uint4*)&Wl[r * 136 + kh];
#pragma unroll
        for (int q = 0; q < 8; ++q) d[q] = s[q];
    }
    __syncthreads();

    floatx4 acc[2][8];
#pragma unroll
    for (int i = 0; i < 2; ++i)
#pragma unroll
        for (int j = 0; j < 8; ++j) acc[i][j] = (floatx4){0.f, 0.f, 0.f, 0.f};

    int ra0 = row0 + wid * 32 + m16;      if (ra0 >= N) ra0 = N - 1;
    int ra1 = row0 + wid * 32 + 16 + m16; if (ra1 >= N) ra1 = N - 1;

#pragma unroll
    for (int c = 0; c < 4; ++c) {
        int k0 = c * 32 + quad * 8;
        bf16x8 a0 = gfrag_dual(A, ra0, 128, k0, isbf);
        bf16x8 a1 = gfrag_dual(A, ra1, 128, k0, isbf);
#pragma unroll
        for (int nt = 0; nt < 8; ++nt) {
            bf16x8 b = ldsfrag(&Wl[(nt * 16 + m16) * 136 + k0]);
            acc[0][nt] = __builtin_amdgcn_mfma_f32_16x16x32_bf16(a0, b, acc[0][nt], 0, 0, 0);
            acc[1][nt] = __builtin_amdgcn_mfma_f32_16x16x32_bf16(a1, b, acc[1][nt], 0, 0, 0);
        }
    }

#pragma unroll
    for (int mt = 0; mt < 2; ++mt) {
        int gr0 = row0 + wid * 32 + mt * 16 + quad * 4;
#pragma unroll
        for (int nt = 0; nt < 8; ++nt) {
            int col = nt * 16 + m16;
            float bb = load_dual(bias, col, isbf);
#pragma unroll
            for (int rg = 0; rg < 4; ++rg) {
                int gr = gr0 + rg;
                if (gr < N) hv[(size_t)gr * 128 + col] = f2b(acc[mt][nt][rg] + bb);
            }
        }
    }
}

// ---------------------------------------------------------------------------
// Fused MLP: out = relu(relu([ctx|nf] @ W1 + b1) @ W2 + b2).
// MLP1: K=256 in 4 chunks of 64 (Wt1 chunk in LDS, A-frags direct from
// global ctx/nf). h -> per-wave LDS (C-layout -> A-layout transform).
// MLP2: K=128 in 2 chunks (Wt2 chunk in LDS, A-frags from h-LDS).
// LDS: 18.4K (Wl) + 34.8K (Hl) = 53.2 KB -> 3 blocks/CU.
// ---------------------------------------------------------------------------
__global__ __launch_bounds__(256) void mlp_fused(const unsigned short* __restrict__ ctx,
                                                 const void* __restrict__ nf,
                                                 const unsigned short* __restrict__ Wt1,
                                                 const void* __restrict__ b1,
                                                 const unsigned short* __restrict__ Wt2,
                                                 const void* __restrict__ b2,
                                                 void* __restrict__ outp,
                                                 const int* __restrict__ flag, int N) {
    __shared__ unsigned short Wl[128 * 72];
    __shared__ unsigned short Hl[4][32 * 136];
    const bool isbf = (*flag != 0);
    const int t = threadIdx.x, wid = t >> 6, lane = t & 63;
    const int m16 = lane & 15, quad = lane >> 4;
    const int row0 = blockIdx.x * 128;

    floatx4 acc[2][8];
#pragma unroll
    for (int i = 0; i < 2; ++i)
#pragma unroll
        for (int j = 0; j < 8; ++j) acc[i][j] = (floatx4){0.f, 0.f, 0.f, 0.f};

    int ra0 = row0 + wid * 32 + m16;      if (ra0 >= N) ra0 = N - 1;
    int ra1 = row0 + wid * 32 + 16 + m16; if (ra1 >= N) ra1 = N - 1;

    // ---- MLP1: acc = [ctx | nf] @ W1 ----
#pragma unroll
    for (int kc = 0; kc < 4; ++kc) {
        {
            int r = t >> 1, kh = (t & 1) * 32;
            const uint4* s = (const uint4*)(Wt1 + (size_t)r * 256 + kc * 64 + kh);
            uint4* d = (uint4*)&Wl[r * 72 + kh];
#pragma unroll
            for (int q = 0; q < 4; ++q) d[q] = s[q];
        }
        __syncthreads();
#pragma unroll
        for (int c = 0; c < 2; ++c) {
            int kl = c * 32 + quad * 8;
            int ka = kc * 64 + kl;
            bf16x8 a0, a1;
            if (ka < 128) {
                union { uint4 u; bf16x8 v; } t0, t1;
                t0.u = *(const uint4*)(ctx + (size_t)ra0 * 128 + ka);
                t1.u = *(const uint4*)(ctx + (size_t)ra1 * 128 + ka);
                a0 = t0.v; a1 = t1.v;
            } else {
                a0 = gfrag_dual(nf, ra0, 128, ka - 128, isbf);
                a1 = gfrag_dual(nf, ra1, 128, ka - 128, isbf);
            }
#pragma unroll
            for (int nt = 0; nt < 8; ++nt) {
                bf16x8 b = ldsfrag(&Wl[(nt * 16 + m16) * 72 + kl]);
                acc[0][nt] = __builtin_amdgcn_mfma_f32_16x16x32_bf16(a0, b, acc[0][nt], 0, 0, 0);
                acc[1][nt] = __builtin_amdgcn_mfma_f32_16x16x32_bf16(a1, b, acc[1][nt], 0, 0, 0);
            }
        }
        __syncthreads();
    }

    // ---- h = relu(acc + b1) -> per-wave LDS [row 0..31][col 0..127] ----
#pragma unroll
    for (int nt = 0; nt < 8; ++nt) {
        int col = nt * 16 + m16;
        float bb = load_dual(b1, col, isbf);
#pragma unroll
        for (int mt = 0; mt < 2; ++mt) {
#pragma unroll
            for (int rg = 0; rg < 4; ++rg) {
                int lr = mt * 16 + quad * 4 + rg;
                float x = acc[mt][nt][rg] + bb;
                Hl[wid][lr * 136 + col] = f2b(x > 0.f ? x : 0.f);
            }
        }
    }

#pragma unroll
    for (int i = 0; i < 2; ++i)
#pragma unroll
        for (int j = 0; j < 8; ++j) acc[i][j] = (floatx4){0.f, 0.f, 0.f, 0.f};

    // ---- MLP2: acc = h @ W2 ----
#pragma unroll
    for (int kc = 0; kc < 2; ++kc) {
        {
            int r = t >> 1, kh = (t & 1) * 32;
            const uint4* s = (const uint4*)(Wt2 + (size_t)r * 128 + kc * 64 + kh);
            uint4* d = (uint4*)&Wl[r * 72 + kh];
#pragma unroll
            for (int q = 0; q < 4; ++q) d[q] = s[q];
        }
        __syncthreads();
#pragma unroll
        for (int c = 0; c < 2; ++c) {
            int kl = c * 32 + quad * 8;
            int ka = kc * 64 + kl;
            bf16x8 a0 = ldsfrag(&Hl[wid][m16 * 136 + ka]);
            bf16x8 a1 = ldsfrag(&Hl[wid][(16 + m16) * 136 + ka]);
#pragma unroll
            for (int nt = 0; nt < 8; ++nt) {
                bf16x8 b = ldsfrag(&Wl[(nt * 16 + m16) * 72 + kl]);
                acc[0][nt] = __builtin_amdgcn_mfma_f32_16x16x32_bf16(a0, b, acc[0][nt], 0, 0, 0);
                acc[1][nt] = __builtin_amdgcn_mfma_f32_16x16x32_bf16(a1, b, acc[1][nt], 0, 0, 0);
            }
        }
        __syncthreads();
    }

    // ---- epilogue: out = relu(acc + b2), dual dtype ----
#pragma unroll
    for (int mt = 0; mt < 2; ++mt) {
        int gr0 = row0 + wid * 32 + mt * 16 + quad * 4;
#pragma unroll
        for (int nt = 0; nt < 8; ++nt) {
            int col = nt * 16 + m16;
            float bb = load_dual(b2, col, isbf);
#pragma unroll
            for (int rg = 0; rg < 4; ++rg) {
                int gr = gr0 + rg;
                if (gr < N) {
                    float x = acc[mt][nt][rg] + bb;
                    x = x > 0.f ? x : 0.f;
                    if (!isbf) ((float*)outp)[(size_t)gr * 128 + col] = x;
                    else       ((unsigned short*)outp)[(size_t)gr * 128 + col] = f2b(x);
                }
            }
        }
    }
}

// ---------------------------------------------------------------------------
extern "C" void kernel_launch(void* const* d_in, const int* in_sizes, int n_in,
                              void* d_out, int out_size, void* d_ws, size_t ws_size,
                              hipStream_t stream) {
    const void* node_feats  = d_in[0];
    const void* edge_logits = d_in[1];
    const void* W_proj      = d_in[2];
    const void* b_proj      = d_in[3];
    const void* W1          = d_in[4];
    const void* b1          = d_in[5];
    const void* W2          = d_in[6];
    const void* b2          = d_in[7];
    const int*  src         = (const int*)d_in[8];
    const int*  dst         = (const int*)d_in[9];

    const int N = in_sizes[0] / 128;
    const int E = in_sizes[8];
    const int NB = (N + BUCKET_NODES - 1) / BUCKET_NODES;   // <= 1024

    char* ws = (char*)d_ws;
    size_t off = 0;
    unsigned short* hv  = (unsigned short*)(ws + off); off += (size_t)N * 256;
    unsigned short* ctx = (unsigned short*)(ws + off); off += (size_t)N * 256;
    uint2* ebuf  = (uint2*)(ws + off); off += (size_t)E * 8;
    uint2* ebuf2 = (uint2*)(ws + off); off += (size_t)E * 8;
    unsigned short* Wtp = (unsigned short*)(ws + off); off += 128 * 128 * 2;
    unsigned short* Wt1 = (unsigned short*)(ws + off); off += 128 * 256 * 2;
    unsigned short* Wt2 = (unsigned short*)(ws + off); off += 128 * 128 * 2;
    int* bcount    = (int*)(ws + off); off += MAX_NB * 4;
    int* bstart    = (int*)(ws + off); off += MAX_NB * 4;
    int* bcursor   = (int*)(ws + off); off += MAX_NB * 4;
    int* row_start = (int*)(ws + off); off += (size_t)N * 4;
    int* ncount    = (int*)(ws + off); off += (size_t)N * 4;
    int* flag      = (int*)(ws + off);

    const int gblocks = (N + 127) / 128;
    const int ebblocks = (E + 8191) / 8192;

    detect_kernel<<<1, 64, 0, stream>>>((const unsigned int*)node_feats, flag);
    hipMemsetAsync(bcount, 0, MAX_NB * 4, stream);

    transpose_all_kernel<<<256, 256, 0, stream>>>(W_proj, W1, W2, Wtp, Wt1, Wt2, flag);

    bhist_kernel<<<ebblocks, 256, 0, stream>>>(dst, bcount, E);
    bscan_kernel<<<1, 256, 0, stream>>>(bcount, bstart, bcursor, NB);
    bappend_kernel<<<ebblocks, 256, 0, stream>>>(dst, src, edge_logits, bcursor,
                                                 ebuf, flag, E);
    bcsr_kernel<<<NB, 256, 0, stream>>>(ebuf, bstart, bcount, ebuf2,
                                        row_start, ncount, N);

    gemm_proj<<<gblocks, 256, 0, stream>>>(node_feats, Wtp, b_proj, hv, flag, N);

    agg_csr_kernel<<<(N + 3) / 4, 256, 0, stream>>>(row_start, ncount, ebuf2,
                                                    (const unsigned int*)hv,
                                                    (unsigned int*)ctx, N);

    mlp_fused<<<gblocks, 256, 0, stream>>>(ctx, node_feats, Wt1, b1, Wt2, b2,
                                           d_out, flag, N);
}